// Round 14
// baseline (1959.825 us; speedup 1.0000x reference)
//
#include <hip/hip_runtime.h>

typedef unsigned short u16;
typedef unsigned int   u32;

// ---------------- problem constants ----------------
constexpr int Bz   = 4;
constexpr int Ni   = 25000;
constexpr int BNi  = Bz * Ni;      // 100000
constexpr int DIN  = 32;
constexpr int D    = 256;
constexpr int Hh   = 8;
constexpr int DH   = 32;
constexpr int Ll   = 6;
constexpr int NQ   = 100;
constexpr int NC1  = 19;
constexpr int HIDd = 1024;

constexpr int CHUNK  = 1250;
constexpr int NCHUNK = Ni / CHUNK;        // 20
constexpr int KSTEP  = 32;
constexpr int NSTEP  = (CHUNK + KSTEP - 1) / KSTEP;   // 40
constexpr size_t PARTB = (size_t)Hh * NCHUNK * 128 * 34;   // floats per batch
constexpr float SM_SCALE = 0.17677669529663687f;  // 1/sqrt(32)

// ---------------- bf16 helpers ----------------
__device__ __forceinline__ u16 f2b(float f) {
    union { __bf16 h; u16 u; } c; c.h = (__bf16)f; return c.u;
}
__device__ __forceinline__ u32 pk2(float a, float b) {
    union { __bf16 h[2]; u32 u; } c; c.h[0] = (__bf16)a; c.h[1] = (__bf16)b; return c.u;
}

__global__ void k_cvt(const float* __restrict__ in, u16* __restrict__ out, int n) {
    for (int i = blockIdx.x * blockDim.x + threadIdx.x; i < n; i += gridDim.x * blockDim.x)
        out[i] = f2b(in[i]);
}

struct CvtJobs { const float* s[9]; u16* d[9]; int n[9]; };
__global__ __launch_bounds__(256) void k_cvtall(CvtJobs j) {
    const int job = blockIdx.y;
    const float* s = j.s[job];
    u16* d = j.d[job];
    const int n = j.n[job];
    for (int i = blockIdx.x * 256 + threadIdx.x; i < n; i += gridDim.x * 256)
        d[i] = f2b(s[i]);
}

// async global->LDS, 16B per lane. LDS dest = wave-uniform base + lane*16.
__device__ __forceinline__ void gload16(const u16* g, u16* l) {
    __builtin_amdgcn_global_load_lds(
        (const __attribute__((address_space(1))) void*)g,
        (__attribute__((address_space(3))) void*)l, 16, 0, 0);
}

// ---------------- MFMA types ----------------
typedef __attribute__((ext_vector_type(8))) __bf16 bf8v;
typedef __attribute__((ext_vector_type(8))) short  s8v;
typedef __attribute__((ext_vector_type(4))) float  f4v;

// ---------------- MFMA input projection ----------------
template<bool DOLN>
__global__ __launch_bounds__(512) void k_inproj(
    const float* __restrict__ x, int row0, int Mloc,
    const u16* __restrict__ w16, const float* __restrict__ bias,
    const float* __restrict__ g, const float* __restrict__ bb,
    u16* __restrict__ outb)
{
    __shared__ u16 Ws[256 * 40];
    __shared__ float Cb[256], Cg[256], Cbb[256];
    const int tid = threadIdx.x, lane = tid & 63, w = tid >> 6;
    const int lr = lane & 15, hi = lane >> 4;

    for (int ch = tid; ch < 1024; ch += 512) {
        int r = ch >> 2, g4 = ch & 3;
        *(uint4*)&Ws[r * 40 + g4 * 8] = *(const uint4*)(w16 + r * 32 + g4 * 8);
    }
    if (tid < 256) {
        Cb[tid] = bias[tid];
        if (DOLN) { Cg[tid] = g[tid]; Cbb[tid] = bb[tid]; }
    }

    const int rloc = blockIdx.x * 128 + w * 16 + lr;
    const int gr = row0 + min(rloc, Mloc - 1);
    bf8v xf;
    {
        const float* xp = x + (size_t)gr * DIN + hi * 8;
        float4 a = *(const float4*)xp, c = *(const float4*)(xp + 4);
        union { s8v s; bf8v b; } u;
        u.s[0] = (short)f2b(a.x); u.s[1] = (short)f2b(a.y);
        u.s[2] = (short)f2b(a.z); u.s[3] = (short)f2b(a.w);
        u.s[4] = (short)f2b(c.x); u.s[5] = (short)f2b(c.y);
        u.s[6] = (short)f2b(c.z); u.s[7] = (short)f2b(c.w);
        xf = u.b;
    }
    __syncthreads();

    f4v acc[16];
    #pragma unroll
    for (int ci = 0; ci < 16; ci++) {
        acc[ci] = (f4v){0.f, 0.f, 0.f, 0.f};
        bf8v af = *(const bf8v*)&Ws[(ci * 16 + lr) * 40 + hi * 8];
        acc[ci] = __builtin_amdgcn_mfma_f32_16x16x32_bf16(af, xf, acc[ci], 0, 0, 0);
    }
    #pragma unroll
    for (int ci = 0; ci < 16; ci++)
        #pragma unroll
        for (int r = 0; r < 4; r++)
            acc[ci][r] += Cb[ci * 16 + hi * 4 + r];

    float mean = 0.f, ri = 1.f;
    if (DOLN) {
        float s = 0.f, q = 0.f;
        #pragma unroll
        for (int ci = 0; ci < 16; ci++)
            #pragma unroll
            for (int r = 0; r < 4; r++) { s += acc[ci][r]; q += acc[ci][r] * acc[ci][r]; }
        s += __shfl_xor(s, 16); s += __shfl_xor(s, 32);
        q += __shfl_xor(q, 16); q += __shfl_xor(q, 32);
        mean = s * (1.f / D);
        float var = q * (1.f / D) - mean * mean;
        ri = rsqrtf(var + 1e-5f);
    }
    if (rloc < Mloc) {
        #pragma unroll
        for (int ci = 0; ci < 16; ci++) {
            float v0[4];
            #pragma unroll
            for (int r = 0; r < 4; r++) {
                float v = acc[ci][r];
                if (DOLN) v = (v - mean) * ri * Cg[ci * 16 + hi * 4 + r] + Cbb[ci * 16 + hi * 4 + r];
                v0[r] = fmaxf(v, 0.f);
            }
            uint2 pkv;
            pkv.x = pk2(v0[0], v0[1]);
            pkv.y = pk2(v0[2], v0[3]);
            *(uint2*)&outb[(size_t)rloc * 256 + ci * 16 + hi * 4] = pkv;
        }
    }
}

// ---------------- row LayerNorm ----------------
__global__ __launch_bounds__(256) void k_ln(
    const float* __restrict__ in, float* __restrict__ out,
    const float* __restrict__ g, const float* __restrict__ b)
{
    const int t = threadIdx.x;
    const int row = blockIdx.x;
    float v = in[(size_t)row * D + t];
    float s = v, q = v * v;
    #pragma unroll
    for (int off = 32; off >= 1; off >>= 1) { s += __shfl_xor(s, off); q += __shfl_xor(q, off); }
    __shared__ float red[2][4];
    const int wid = t >> 6;
    if ((t & 63) == 0) { red[0][wid] = s; red[1][wid] = q; }
    __syncthreads();
    float S = red[0][0] + red[0][1] + red[0][2] + red[0][3];
    float Q = red[1][0] + red[1][1] + red[1][2] + red[1][3];
    float m   = S * (1.f / D);
    float var = Q * (1.f / D) - m * m;
    float ri  = rsqrtf(var + 1e-5f);
    out[(size_t)row * D + t] = (v - m) * ri * g[t] + b[t];
}

__global__ __launch_bounds__(256) void k_bcast(const float* __restrict__ qe, float* __restrict__ q)
{
    const int t = threadIdx.x;
    const int r = blockIdx.x;
    q[(size_t)r * D + t] = qe[(size_t)(r % NQ) * D + t];
}

// ---------------- fp32 tile GEMM (cls head only) ----------------
template<int BM, int BN, int TM, int TN>
__global__ __launch_bounds__(256) void k_gemm(
    const float* __restrict__ A, const float* __restrict__ W,
    const float* __restrict__ bias, const float* __restrict__ resid,
    float* __restrict__ C, int M, int N, int K, int relu)
{
    constexpr int BK = 16;
    constexpr int TX = BN / TN, TY = BM / TM;
    static_assert(TX * TY == 256, "block must be 256 threads");
    __shared__ float As[BK][BM + 4];
    __shared__ float Ws[BK][BN + 4];

    const int tid = threadIdx.x;
    const int tx = tid % TX, ty = tid / TX;
    const int row0 = blockIdx.y * BM, col0 = blockIdx.x * BN;

    float acc[TM][TN];
    #pragma unroll
    for (int i = 0; i < TM; i++)
        #pragma unroll
        for (int j = 0; j < TN; j++) acc[i][j] = 0.f;

    for (int k0 = 0; k0 < K; k0 += BK) {
        __syncthreads();
        for (int idx = tid; idx < BM * (BK / 4); idx += 256) {
            int r = idx / (BK / 4), c4 = idx % (BK / 4);
            int gr = row0 + r;
            float4 v;
            if (gr < M) v = *(const float4*)(A + (size_t)gr * K + k0 + c4 * 4);
            else { v.x = v.y = v.z = v.w = 0.f; }
            As[c4*4+0][r] = v.x; As[c4*4+1][r] = v.y; As[c4*4+2][r] = v.z; As[c4*4+3][r] = v.w;
        }
        for (int idx = tid; idx < BN * (BK / 4); idx += 256) {
            int n = idx / (BK / 4), c4 = idx % (BK / 4);
            int gn = col0 + n;
            float4 v;
            if (gn < N) v = *(const float4*)(W + (size_t)gn * K + k0 + c4 * 4);
            else { v.x = v.y = v.z = v.w = 0.f; }
            Ws[c4*4+0][n] = v.x; Ws[c4*4+1][n] = v.y; Ws[c4*4+2][n] = v.z; Ws[c4*4+3][n] = v.w;
        }
        __syncthreads();
        #pragma unroll
        for (int kk = 0; kk < BK; kk++) {
            float a[TM], bb[TN];
            #pragma unroll
            for (int i = 0; i < TM; i++) a[i] = As[kk][ty * TM + i];
            #pragma unroll
            for (int j = 0; j < TN; j++) bb[j] = Ws[kk][tx * TN + j];
            #pragma unroll
            for (int i = 0; i < TM; i++)
                #pragma unroll
                for (int j = 0; j < TN; j++)
                    acc[i][j] = fmaf(a[i], bb[j], acc[i][j]);
        }
    }

    #pragma unroll
    for (int i = 0; i < TM; i++) {
        int gr = row0 + ty * TM + i;
        if (gr >= M) continue;
        #pragma unroll
        for (int j = 0; j < TN; j++) {
            int gn = col0 + tx * TN + j;
            if (gn >= N) continue;
            float v = acc[i][j];
            if (bias)  v += bias[gn];
            if (resid) v += resid[(size_t)gr * N + gn];
            if (relu)  v = fmaxf(v, 0.f);
            C[(size_t)gr * N + gn] = v;
        }
    }
}

// ---------------- mm_small: bf16 MFMA GEMM, fp32 A, fp32 out ----------------
template<bool RELU>
__global__ __launch_bounds__(256) void mm_small(
    const float* __restrict__ A, const u16* __restrict__ W,
    const float* __restrict__ bias, const float* __restrict__ resid,
    float* __restrict__ C, int M, int N, int K)
{
    __shared__ u16 As[64 * 40];
    __shared__ u16 Bs[64 * 40];
    const int tid  = threadIdx.x;
    const int lane = tid & 63, w = tid >> 6;
    const int wm = w >> 1, wn = w & 1;
    const int row0 = blockIdx.y * 64, col0 = blockIdx.x * 64;
    const int lr = lane & 15, hi = lane >> 4;

    f4v acc[2][2];
    #pragma unroll
    for (int i = 0; i < 2; i++)
        #pragma unroll
        for (int j = 0; j < 2; j++) acc[i][j] = (f4v){0.f, 0.f, 0.f, 0.f};

    const int sr = tid >> 2, sc = (tid & 3) * 8;
    const int ga = min(row0 + sr, M - 1);
    const int gw = min(col0 + sr, N - 1);

    for (int k0 = 0; k0 < K; k0 += 32) {
        __syncthreads();
        {
            const float* ap = A + (size_t)ga * K + k0 + sc;
            float4 a = *(const float4*)ap, c = *(const float4*)(ap + 4);
            uint4 u;
            u.x = pk2(a.x, a.y); u.y = pk2(a.z, a.w);
            u.z = pk2(c.x, c.y); u.w = pk2(c.z, c.w);
            *(uint4*)&As[sr * 40 + sc] = u;
            *(uint4*)&Bs[sr * 40 + sc] = *(const uint4*)(W + (size_t)gw * K + k0 + sc);
        }
        __syncthreads();
        bf8v a0 = *(const bf8v*)&As[(wm * 32      + lr) * 40 + hi * 8];
        bf8v a1 = *(const bf8v*)&As[(wm * 32 + 16 + lr) * 40 + hi * 8];
        bf8v b0 = *(const bf8v*)&Bs[(wn * 32      + lr) * 40 + hi * 8];
        bf8v b1 = *(const bf8v*)&Bs[(wn * 32 + 16 + lr) * 40 + hi * 8];
        acc[0][0] = __builtin_amdgcn_mfma_f32_16x16x32_bf16(a0, b0, acc[0][0], 0, 0, 0);
        acc[0][1] = __builtin_amdgcn_mfma_f32_16x16x32_bf16(a0, b1, acc[0][1], 0, 0, 0);
        acc[1][0] = __builtin_amdgcn_mfma_f32_16x16x32_bf16(a1, b0, acc[1][0], 0, 0, 0);
        acc[1][1] = __builtin_amdgcn_mfma_f32_16x16x32_bf16(a1, b1, acc[1][1], 0, 0, 0);
    }

    const int crl = hi * 4, ccl = lr;
    #pragma unroll
    for (int mi = 0; mi < 2; mi++)
        #pragma unroll
        for (int ni = 0; ni < 2; ni++)
            #pragma unroll
            for (int r = 0; r < 4; r++) {
                int grow = row0 + wm * 32 + mi * 16 + crl + r;
                int gcol = col0 + wn * 32 + ni * 16 + ccl;
                if (grow < M && gcol < N) {
                    float v = acc[mi][ni][r];
                    if (bias)  v += bias[gcol];
                    if (resid) v += resid[(size_t)grow * N + gcol];
                    if (RELU)  v = fmaxf(v, 0.f);
                    C[(size_t)grow * N + gcol] = v;
                }
            }
}

// ---------------- mm128 (mask path): gload_lds + XCD swizzle, coalesced bf16 store ----
template<bool OUTBF>
__global__ __launch_bounds__(256) void mm128(
    const u16* __restrict__ A, const u16* __restrict__ W,
    const float* __restrict__ bias, void* __restrict__ Cv,
    int M, int N, int K, long long sA, long long sW, long long sC,
    int zmod, long long sW2, long long sBias)
{
    __shared__ u16 sm[8192];
    u16* As = sm;
    u16* Bs = sm + 4096;

    const int gx = gridDim.x, gy = gridDim.y;
    const int total = gx * gy * (int)gridDim.z;
    const int flat = blockIdx.x + gx * (blockIdx.y + gy * blockIdx.z);
    const int q8 = total >> 3, r8 = total & 7;
    const int xcd = flat & 7, blk = flat >> 3;
    const int swz = (xcd < r8 ? xcd * (q8 + 1) : r8 * (q8 + 1) + (xcd - r8) * q8) + blk;
    const int bx = swz % gx, by = (swz / gx) % gy, bz = swz / (gx * gy);

    const int aidx = bz % zmod, widx = bz / zmod;
    A += (size_t)aidx * sA;
    W += (size_t)aidx * sW + (size_t)widx * sW2;
    if (bias) bias += (size_t)widx * sBias;
    const int tid = threadIdx.x, lane = tid & 63, w = tid >> 6;
    const int wm = w >> 1, wn = w & 1;
    const int row0 = by * 128, col0 = bx * 128;
    const int lr = lane & 15, hi = lane >> 4;
    const int srow = lane >> 2, scol = (lane & 3) * 8;

    f4v acc[4][4];
    #pragma unroll
    for (int i = 0; i < 4; i++)
        #pragma unroll
        for (int j = 0; j < 4; j++) acc[i][j] = (f4v){0.f, 0.f, 0.f, 0.f};

    for (int k0 = 0; k0 < K; k0 += 32) {
        __syncthreads();
        #pragma unroll
        for (int i = 0; i < 2; i++) {
            const int c = w * 2 + i;
            const int row = c * 16 + srow;
            const int gra = min(row0 + row, M - 1);
            const int grb = min(col0 + row, N - 1);
            gload16(A + (size_t)gra * K + k0 + scol, &As[c * 512]);
            gload16(W + (size_t)grb * K + k0 + scol, &Bs[c * 512]);
        }
        __syncthreads();
        bf8v a[4], bb[4];
        #pragma unroll
        for (int mi = 0; mi < 4; mi++)
            a[mi] = *(const bf8v*)&As[(wm * 64 + mi * 16 + lr) * 32 + hi * 8];
        #pragma unroll
        for (int ni = 0; ni < 4; ni++)
            bb[ni] = *(const bf8v*)&Bs[(wn * 64 + ni * 16 + lr) * 32 + hi * 8];
        #pragma unroll
        for (int mi = 0; mi < 4; mi++)
            #pragma unroll
            for (int ni = 0; ni < 4; ni++)
                acc[mi][ni] = __builtin_amdgcn_mfma_f32_16x16x32_bf16(a[mi], bb[ni], acc[mi][ni], 0, 0, 0);
    }

    if (OUTBF) {
        #pragma unroll
        for (int h0 = 0; h0 < 2; h0++) {
            __syncthreads();
            if (wm == h0) {
                #pragma unroll
                for (int mi = 0; mi < 4; mi++)
                    #pragma unroll
                    for (int ni = 0; ni < 4; ni++) {
                        int gcol = col0 + wn * 64 + ni * 16 + lr;
                        float bv = bias ? bias[gcol] : 0.f;
                        #pragma unroll
                        for (int r = 0; r < 4; r++) {
                            int lrow = mi * 16 + hi * 4 + r;
                            sm[lrow * 128 + wn * 64 + ni * 16 + lr] = f2b(acc[mi][ni][r] + bv);
                        }
                    }
            }
            __syncthreads();
            u16* Cb16 = (u16*)Cv + (size_t)bz * sC;
            #pragma unroll
            for (int j = 0; j < 4; j++) {
                int idx = tid + j * 256;
                int lrow = idx >> 4, c16 = idx & 15;
                int grow = row0 + h0 * 64 + lrow;
                if (grow < M)
                    *(uint4*)(Cb16 + (size_t)grow * N + col0 + c16 * 8) =
                        *(const uint4*)&sm[lrow * 128 + c16 * 8];
            }
        }
    } else {
        const int crl = hi * 4, ccl = lr;
        float* Cf = (float*)Cv + (size_t)bz * sC;
        #pragma unroll
        for (int mi = 0; mi < 4; mi++)
            #pragma unroll
            for (int ni = 0; ni < 4; ni++)
                #pragma unroll
                for (int r = 0; r < 4; r++) {
                    int grow = row0 + wm * 64 + mi * 16 + crl + r;
                    int gcol = col0 + wn * 64 + ni * 16 + ccl;
                    if (grow < M && gcol < N) {
                        float v = acc[mi][ni][r];
                        if (bias) v += bias[gcol];
                        Cf[(size_t)grow * N + gcol] = v;
                    }
                }
    }
}

// ---------------- k_fused: KV projection + flash attention, fused ----------------
// grid (NCHUNK, Hh, Bz) remapped so one (chunk,batch) group's 8 heads share an XCD.
// Per 32-key step: stage inst rows -> project K (waves 0-3) & V (waves 4-7) via MFMA
// -> Ks[key][d] / Vt[d][key] in LDS -> QK^T (swapped) -> softmax -> PV.
// Pt aliases the (dead-after-proj) inst tile. LDS total ~55.8 KB.
__global__ __launch_bounds__(512) void k_fused(
    const float* __restrict__ qbuf, const u16* __restrict__ instb,
    const u16* __restrict__ wk,          // K rows [256x256]; V rows follow at +D*D
    const float* __restrict__ bkv,       // K bias [0..D), V bias [D..2D)
    float* __restrict__ part)
{
    __shared__ u16 Wks[32 * 264];
    __shared__ u16 Wvs[32 * 264];
    __shared__ u16 instT[32 * 264];      // also holds Pt (8 waves x 16 x 40)
    __shared__ u16 Ks[32 * 40];
    __shared__ u16 Vt[32 * 40];
    u16* Pt = instT;

    // XCD grouping: hw flat id f -> xcd=f&7; give each (chunk,batch) group one XCD
    const int f = blockIdx.x + NCHUNK * (blockIdx.y + Hh * (int)blockIdx.z);
    const int xcd = f & 7, slot = f >> 3;
    const int g = xcd * 10 + (slot >> 3);     // 80 groups (20 chunks x 4 batches)
    const int h = slot & 7;
    const int c = g % NCHUNK, b = g / NCHUNK;

    const int tid = threadIdx.x, lane = tid & 63, w = tid >> 6;
    const int lr = lane & 15, hi = lane >> 4;
    const int k0loc = c * CHUNK;
    const u16* instB = instb + (size_t)b * Ni * D;
    const u16* wkh = wk + (size_t)(h * DH) * D;
    const u16* wvh = wk + (size_t)D * D + (size_t)(h * DH) * D;

    // stage W once (2048 uint8-chunks? 2*32 rows * 32 col-chunks)
    for (int idx = tid; idx < 2048; idx += 512) {
        int which = idx >> 10;
        int r = (idx >> 5) & 31, c8 = idx & 31;
        const u16* src = (which ? wvh : wkh) + (size_t)r * D + c8 * 8;
        u16* dst = (which ? Wvs : Wks) + r * 264 + c8 * 8;
        *(uint4*)dst = *(const uint4*)src;
    }

    // Q fragment: row=q=lr (per wave 16 q), k=d=hi*8..+8, pre-scaled
    const int qt = w * 16 + lr;
    const int qg = b * NQ + min(qt, NQ - 1);
    bf8v qf;
    {
        const float* Qp = qbuf + (size_t)qg * D + h * DH + hi * 8;
        union { s8v s; bf8v b2; } qu;
        #pragma unroll
        for (int j = 0; j < 8; j++) qu.s[j] = (short)f2b(Qp[j] * SM_SCALE);
        qf = qu.b2;
    }

    // projection role: waves 0-3 -> K tile (kt,dt); waves 4-7 -> V tile
    const int isV = w >> 2;
    const int w2 = w & 3;
    const int ktw = w2 & 1, dtw = w2 >> 1;
    float kb = 0.f, vb[4];
    if (!isV) {
        kb = bkv[h * DH + dtw * 16 + lr];
    } else {
        #pragma unroll
        for (int r = 0; r < 4; r++) vb[r] = bkv[D + h * DH + dtw * 16 + hi * 4 + r];
    }

    float m = -1e30f, l = 0.f;
    f4v o0 = (f4v){0.f,0.f,0.f,0.f}, o1 = (f4v){0.f,0.f,0.f,0.f};

    for (int s = 0; s < NSTEP; s++) {
        const int ck = k0loc + s * KSTEP;
        const int nv = min(KSTEP, k0loc + CHUNK - ck);
        __syncthreads();                       // prev step's PV done (Pt region reuse)
        // stage inst tile: 32 rows x 256 bf16
        for (int idx = tid; idx < 1024; idx += 512) {
            int r = idx >> 5, c8 = idx & 31;
            int grow = min(ck + r, Ni - 1);
            *(uint4*)&instT[r * 264 + c8 * 8] =
                *(const uint4*)(instB + (size_t)grow * D + c8 * 8);
        }
        __syncthreads();
        // projection: one 16x16 output tile per wave over K=256
        f4v pacc = (f4v){0.f,0.f,0.f,0.f};
        #pragma unroll
        for (int kk = 0; kk < 8; kk++) {
            bf8v af, bf;
            if (!isV) {
                af = *(const bf8v*)&instT[(ktw * 16 + lr) * 264 + kk * 32 + hi * 8];
                bf = *(const bf8v*)&Wks[(dtw * 16 + lr) * 264 + kk * 32 + hi * 8];
            } else {
                af = *(const bf8v*)&Wvs[(dtw * 16 + lr) * 264 + kk * 32 + hi * 8];
                bf = *(const bf8v*)&instT[(ktw * 16 + lr) * 264 + kk * 32 + hi * 8];
            }
            pacc = __builtin_amdgcn_mfma_f32_16x16x32_bf16(af, bf, pacc, 0, 0, 0);
        }
        if (!isV) {
            // D[key][d]: col=d=lr, row=key=hi*4+r  -> Ks[key][d]
            #pragma unroll
            for (int r = 0; r < 4; r++)
                Ks[(ktw * 16 + hi * 4 + r) * 40 + dtw * 16 + lr] = f2b(pacc[r] + kb);
        } else {
            // D[d][key]: col=key=lr, row=d=hi*4+r  -> Vt[d][key]
            #pragma unroll
            for (int r = 0; r < 4; r++)
                Vt[(dtw * 16 + hi * 4 + r) * 40 + ktw * 16 + lr] = f2b(pacc[r] + vb[r]);
        }
        __syncthreads();

        // QK^T (swapped): S[key][q], 32 keys = 2 key-frags
        f4v sf[2];
        #pragma unroll
        for (int j = 0; j < 2; j++) {
            bf8v kf = *(const bf8v*)&Ks[(j * 16 + lr) * 40 + hi * 8];
            sf[j] = (f4v){0.f,0.f,0.f,0.f};
            sf[j] = __builtin_amdgcn_mfma_f32_16x16x32_bf16(kf, qf, sf[j], 0, 0, 0);
        }
        float sv[8];
        #pragma unroll
        for (int j = 0; j < 2; j++)
            #pragma unroll
            for (int r = 0; r < 4; r++) {
                int key0 = j * 16 + hi * 4 + r;
                sv[j * 4 + r] = (key0 < nv) ? sf[j][r] : -1e30f;
            }
        float smax = sv[0];
        #pragma unroll
        for (int j = 1; j < 8; j++) smax = fmaxf(smax, sv[j]);
        smax = fmaxf(smax, __shfl_xor(smax, 16));
        smax = fmaxf(smax, __shfl_xor(smax, 32));
        float mnew  = fmaxf(m, smax);
        float scale = __expf(m - mnew);
        m = mnew;

        float pv[8];
        float psum = 0.f;
        #pragma unroll
        for (int j = 0; j < 8; j++) { pv[j] = __expf(sv[j] - mnew); psum += pv[j]; }
        psum += __shfl_xor(psum, 16);
        psum += __shfl_xor(psum, 32);
        l = l * scale + psum;

        // P tile write (row q=lr, 32 keys, pitch 40) into Pt (aliases instT)
        u16* pw = &Pt[(size_t)w * 640 + lr * 40];
        #pragma unroll
        for (int j = 0; j < 2; j++) {
            *(u32*)&pw[j * 16 + hi * 4]     = pk2(pv[j*4+0], pv[j*4+1]);
            *(u32*)&pw[j * 16 + hi * 4 + 2] = pk2(pv[j*4+2], pv[j*4+3]);
        }

        const int qb4 = hi * 4;
        float f0 = __shfl(scale, qb4 + 0);
        float f1 = __shfl(scale, qb4 + 1);
        float f2 = __shfl(scale, qb4 + 2);
        float f3 = __shfl(scale, qb4 + 3);
        o0[0] *= f0; o0[1] *= f1; o0[2] *= f2; o0[3] *= f3;
        o1[0] *= f0; o1[1] *= f1; o1[2] *= f2; o1[3] *= f3;

        // PV: O[q][d] += P[q][32 keys] * Vt[d][32 keys]
        bf8v pf  = *(const bf8v*)&Pt[(size_t)w * 640 + lr * 40 + hi * 8];
        bf8v vf0 = *(const bf8v*)&Vt[lr * 40 + hi * 8];
        bf8v vf1 = *(const bf8v*)&Vt[(16 + lr) * 40 + hi * 8];
        o0 = __builtin_amdgcn_mfma_f32_16x16x32_bf16(pf, vf0, o0, 0, 0, 0);
        o1 = __builtin_amdgcn_mfma_f32_16x16x32_bf16(pf, vf1, o1, 0, 0, 0);
    }

    float* pp = part + (size_t)b * PARTB;
    const size_t pbase = ((size_t)(h * NCHUNK + c) * 128) * 34;
    #pragma unroll
    for (int r = 0; r < 4; r++) {
        int qtr = w * 16 + hi * 4 + r;
        pp[pbase + (size_t)qtr * 34 + 2 + lr]      = o0[r];
        pp[pbase + (size_t)qtr * 34 + 2 + 16 + lr] = o1[r];
    }
    if (lane < 16) {
        pp[pbase + (size_t)(w * 16 + lane) * 34 + 0] = m;
        pp[pbase + (size_t)(w * 16 + lane) * 34 + 1] = l;
    }
}

__global__ __launch_bounds__(64) void k_fmerge(const float* __restrict__ part,
                                               float* __restrict__ abuf, int bBase, size_t pStride)
{
    const float* pz = part + (size_t)blockIdx.y * pStride;
    const int b = bBase + blockIdx.y;
    const int t = threadIdx.x;
    const int hq = blockIdx.x;
    const int h = hq / NQ, q = hq % NQ;
    float mmax = -1e30f;
    for (int c = 0; c < NCHUNK; c++)
        mmax = fmaxf(mmax, pz[((size_t)(h * NCHUNK + c) * 128 + q) * 34]);
    float L = 0.f, a = 0.f;
    for (int c = 0; c < NCHUNK; c++) {
        const float* p = &pz[((size_t)(h * NCHUNK + c) * 128 + q) * 34];
        float wv = __expf(p[0] - mmax);
        L += wv * p[1];
        if (t < DH) a += wv * p[2 + t];
    }
    if (t < DH)
        abuf[((size_t)(b * NQ + q)) * D + h * DH + t] = a / L;
}

// ---------------- self-attention (100x100 per (b,h)) ----------------
__global__ __launch_bounds__(128) void k_sattn(const float* __restrict__ sqkv, float* __restrict__ abuf)
{
    const int tid = threadIdx.x;
    const int bh = blockIdx.x;
    const int b = bh >> 3, h = bh & 7;
    __shared__ float Ks[NQ][DH], Vs[NQ][DH];
    for (int idx = tid; idx < NQ * 8; idx += 128) {
        int kk = idx >> 3, f4 = idx & 7;
        const float* base = sqkv + ((size_t)(b * NQ + kk)) * (3 * D) + h * DH;
        *(float4*)&Ks[kk][f4 * 4] = *(const float4*)(base + D + f4 * 4);
        *(float4*)&Vs[kk][f4 * 4] = *(const float4*)(base + 2 * D + f4 * 4);
    }
    float qr[DH];
    const int q = tid;
    if (q < NQ) {
        const float* Qp = sqkv + ((size_t)(b * NQ + q)) * (3 * D) + h * DH;
        #pragma unroll
        for (int d = 0; d < DH; d += 4) {
            float4 v = *(const float4*)(Qp + d);
            qr[d] = v.x * SM_SCALE; qr[d+1] = v.y * SM_SCALE;
            qr[d+2] = v.z * SM_SCALE; qr[d+3] = v.w * SM_SCALE;
        }
    } else {
        #pragma unroll
        for (int d = 0; d < DH; d++) qr[d] = 0.f;
    }
    __syncthreads();
    float m = -1e30f, l = 0.f, acc[DH];
    #pragma unroll
    for (int d = 0; d < DH; d++) acc[d] = 0.f;
    for (int kk = 0; kk < NQ; kk++) {
        float sc = 0.f;
        #pragma unroll
        for (int d = 0; d < DH; d++) sc += qr[d] * Ks[kk][d];
        if (sc > m) {
            float r = __expf(m - sc);
            l *= r;
            #pragma unroll
            for (int d = 0; d < DH; d++) acc[d] *= r;
            m = sc;
        }
        float p = __expf(sc - m);
        l += p;
        #pragma unroll
        for (int d = 0; d < DH; d++) acc[d] += p * Vs[kk][d];
    }
    if (q < NQ) {
        float li = 1.f / l;
        float* o = abuf + ((size_t)(b * NQ + q)) * D + h * DH;
        #pragma unroll
        for (int d = 0; d < DH; d++) o[d] = acc[d] * li;
    }
}

// ---------------- host ----------------
extern "C" void kernel_launch(void* const* d_in, const int* in_sizes, int n_in,
                              void* d_out, int out_size, void* d_ws, size_t ws_size,
                              hipStream_t stream)
{
    const float* x        = (const float*)d_in[0];
    const float* ip_w     = (const float*)d_in[2];
    const float* ip_b     = (const float*)d_in[3];
    const float* ip_g     = (const float*)d_in[4];
    const float* ip_bb    = (const float*)d_in[5];
    const float* xm_w1    = (const float*)d_in[6];
    const float* xm_b1    = (const float*)d_in[7];
    const float* xm_w2    = (const float*)d_in[8];
    const float* xm_b2    = (const float*)d_in[9];
    const float* qe       = (const float*)d_in[10];
    const float* ca_wqkv  = (const float*)d_in[11];
    const float* ca_bqkv  = (const float*)d_in[12];
    const float* ca_wo    = (const float*)d_in[13];
    const float* ca_bo    = (const float*)d_in[14];
    const float* sa_wqkv  = (const float*)d_in[15];
    const float* sa_bqkv  = (const float*)d_in[16];
    const float* sa_wo    = (const float*)d_in[17];
    const float* sa_bo    = (const float*)d_in[18];
    const float* sa_ln_g  = (const float*)d_in[19];
    const float* sa_ln_b  = (const float*)d_in[20];
    const float* ffn_w1   = (const float*)d_in[21];
    const float* ffn_b1   = (const float*)d_in[22];
    const float* ffn_w2   = (const float*)d_in[23];
    const float* ffn_b2   = (const float*)d_in[24];
    const float* ffn_ln_g = (const float*)d_in[25];
    const float* ffn_ln_b = (const float*)d_in[26];
    const float* out_ln_g = (const float*)d_in[27];
    const float* out_ln_b = (const float*)d_in[28];
    const float* cls_w1   = (const float*)d_in[29];
    const float* cls_b1   = (const float*)d_in[30];
    const float* cls_w2   = (const float*)d_in[31];
    const float* cls_b2   = (const float*)d_in[32];
    float* out = (float*)d_out;

    // measured: ws_size in [210, 430) MB -> fused batched path always fits (~140 MB)
    if (ws_size < 160000000ull) return;

    char* wp = (char*)d_ws;
    auto alloc = [&](size_t bytes) -> char* {
        char* r = wp; wp += (bytes + 255) & ~(size_t)255; return r;
    };
    u16*   instb = (u16*)  alloc((size_t)BNi * D * 2);            // 51.2 MB
    u16*   kvb   = (u16*)  alloc((size_t)Bz * Ni * D * 2);        // 51.2 MB (mask path)
    float* part  = (float*)alloc((size_t)Bz * PARTB * 4);         // 11.1 MB
    float* qbuf  = (float*)alloc(409600);
    float* abuf  = (float*)alloc(409600);
    float* sqkv  = (float*)alloc(1228800);
    float* f1b   = (float*)alloc(1638400);
    float* qA    = (float*)alloc(409600);
    float* qB    = (float*)alloc(409600);
    u16*   ipw16 = (u16*)  alloc(256 * 32 * 2);
    u16*   xw116 = (u16*)  alloc(256 * 32 * 2);
    u16*   xw216 = (u16*)  alloc((size_t)D * D * 2);
    u16*   caq16 = (u16*)  alloc((size_t)Ll * 3 * D * D * 2);
    u16*   saq16 = (u16*)  alloc((size_t)Ll * 3 * D * D * 2);
    u16*   cao16 = (u16*)  alloc((size_t)Ll * D * D * 2);
    u16*   sao16 = (u16*)  alloc((size_t)Ll * D * D * 2);
    u16*   fw116 = (u16*)  alloc((size_t)Ll * HIDd * D * 2);
    u16*   fw216 = (u16*)  alloc((size_t)Ll * D * HIDd * 2);
    u16*   qnb   = (u16*)  alloc((size_t)Bz * NQ * D * 2);

    {
        CvtJobs j;
        j.s[0] = ip_w;    j.d[0] = ipw16; j.n[0] = 256 * 32;
        j.s[1] = xm_w1;   j.d[1] = xw116; j.n[1] = 256 * 32;
        j.s[2] = xm_w2;   j.d[2] = xw216; j.n[2] = D * D;
        j.s[3] = ca_wqkv; j.d[3] = caq16; j.n[3] = Ll * 3 * D * D;
        j.s[4] = sa_wqkv; j.d[4] = saq16; j.n[4] = Ll * 3 * D * D;
        j.s[5] = ca_wo;   j.d[5] = cao16; j.n[5] = Ll * D * D;
        j.s[6] = sa_wo;   j.d[6] = sao16; j.n[6] = Ll * D * D;
        j.s[7] = ffn_w1;  j.d[7] = fw116; j.n[7] = Ll * HIDd * D;
        j.s[8] = ffn_w2;  j.d[8] = fw216; j.n[8] = Ll * D * HIDd;
        k_cvtall<<<dim3(48, 9), 256, 0, stream>>>(j);
    }

    k_inproj<true><<<(BNi + 127) / 128, 512, 0, stream>>>(
        x, 0, BNi, ipw16, ip_b, ip_g, ip_bb, instb);
    k_bcast<<<Bz * NQ, 256, 0, stream>>>(qe, qA);

    float* qcur = qA;
    float* qtmp = qB;

    for (int i = 0; i < Ll; i++) {
        const u16*   wq16 = caq16 + (size_t)i * 3 * D * D;
        const float* bqkv = ca_bqkv + (size_t)i * 3 * D;
        // Q projection
        mm_small<false><<<dim3(4, 7), 256, 0, stream>>>(
            qcur, wq16, bqkv, nullptr, qbuf, Bz * NQ, D, D);
        // fused KV-proj + flash attention
        k_fused<<<dim3(NCHUNK, Hh, Bz), 512, 0, stream>>>(
            qbuf, instb, wq16 + (size_t)D * D, bqkv + D, part);
        k_fmerge<<<dim3(Hh * NQ, Bz), 64, 0, stream>>>(part, abuf, 0, PARTB);
        // CA out-proj + pure residual
        mm_small<false><<<dim3(4, 7), 256, 0, stream>>>(
            abuf, cao16 + (size_t)i * D * D, ca_bo + (size_t)i * D, qcur, qtmp,
            Bz * NQ, D, D);
        { float* t2 = qcur; qcur = qtmp; qtmp = t2; }
        // self-attention
        mm_small<false><<<dim3(12, 7), 256, 0, stream>>>(
            qcur, saq16 + (size_t)i * 3 * D * D, sa_bqkv + (size_t)i * 3 * D, nullptr, sqkv,
            Bz * NQ, 3 * D, D);
        k_sattn<<<Bz * Hh, 128, 0, stream>>>(sqkv, abuf);
        mm_small<false><<<dim3(4, 7), 256, 0, stream>>>(
            abuf, sao16 + (size_t)i * D * D, sa_bo + (size_t)i * D, qcur, qtmp,
            Bz * NQ, D, D);
        k_ln<<<Bz * NQ, 256, 0, stream>>>(qtmp, qtmp, sa_ln_g + i * D, sa_ln_b + i * D);
        { float* t2 = qcur; qcur = qtmp; qtmp = t2; }
        // FFN
        mm_small<true><<<dim3(16, 7), 256, 0, stream>>>(
            qcur, fw116 + (size_t)i * HIDd * D, ffn_b1 + (size_t)i * HIDd, nullptr, f1b,
            Bz * NQ, HIDd, D);
        mm_small<false><<<dim3(4, 7), 256, 0, stream>>>(
            f1b, fw216 + (size_t)i * D * HIDd, ffn_b2 + (size_t)i * D, qcur, qtmp,
            Bz * NQ, D, HIDd);
        k_ln<<<Bz * NQ, 256, 0, stream>>>(qtmp, qtmp, ffn_ln_g + i * D, ffn_ln_b + i * D);
        { float* t2 = qcur; qcur = qtmp; qtmp = t2; }
    }

    // final LN into qbuf
    float* qn = qbuf;
    k_ln<<<Bz * NQ, 256, 0, stream>>>(qcur, qn, out_ln_g, out_ln_b);
    // classification head (fp32)
    k_gemm<64,64,4,4><<<dim3(4, 7), 256, 0, stream>>>(
        qn, cls_w1, cls_b1, nullptr, abuf, Bz * NQ, D, D, 1);
    k_gemm<64,64,4,4><<<dim3(1, 7), 256, 0, stream>>>(
        abuf, cls_w2, cls_b2, nullptr, out, Bz * NQ, NC1, D, 0);

    // mask path (instb region reused for h1; kvb holds maskf)
    k_cvt<<<128, 256, 0, stream>>>(qn, qnb, Bz * NQ * D);
    k_inproj<false><<<(BNi + 127) / 128, 512, 0, stream>>>(
        x, 0, BNi, xw116, xm_b1, nullptr, nullptr, instb);
    mm128<true><<<dim3(2, 196, 4), 256, 0, stream>>>(
        instb, xw216, xm_b2, kvb, Ni, D, D,
        (long long)Ni * D, 0, (long long)Ni * D, 4, 0, 0);
    mm128<false><<<dim3(196, 1, 4), 256, 0, stream>>>(
        qnb, kvb, nullptr, out + Bz * NQ * NC1, NQ, Ni, D,
        (long long)NQ * D, (long long)Ni * D, (long long)NQ * Ni, 4, 0, 0);
}

// Round 15
// 1696.965 us; speedup vs baseline: 1.1549x; 1.1549x over previous
//
#include <hip/hip_runtime.h>

typedef unsigned short u16;
typedef unsigned int   u32;

// ---------------- problem constants ----------------
constexpr int Bz   = 4;
constexpr int Ni   = 25000;
constexpr int BNi  = Bz * Ni;      // 100000
constexpr int DIN  = 32;
constexpr int D    = 256;
constexpr int Hh   = 8;
constexpr int DH   = 32;
constexpr int Ll   = 6;
constexpr int NQ   = 100;
constexpr int NC1  = 19;
constexpr int HIDd = 1024;

constexpr int CHUNK  = 1250;
constexpr int NCHUNK = Ni / CHUNK;        // 20
constexpr size_t PARTB = (size_t)Hh * NCHUNK * 128 * 34;   // floats per batch
constexpr float SM_SCALE = 0.17677669529663687f;  // 1/sqrt(32)

// ---------------- bf16 helpers (native RNE casts -> v_cvt_pk fusion) ----------------
__device__ __forceinline__ u16 f2b(float f) {
    union { __bf16 h; u16 u; } c; c.h = (__bf16)f; return c.u;
}
__device__ __forceinline__ u32 pk2(float a, float b) {
    union { __bf16 h[2]; u32 u; } c; c.h[0] = (__bf16)a; c.h[1] = (__bf16)b; return c.u;
}

__global__ void k_cvt(const float* __restrict__ in, u16* __restrict__ out, int n) {
    for (int i = blockIdx.x * blockDim.x + threadIdx.x; i < n; i += gridDim.x * blockDim.x)
        out[i] = f2b(in[i]);
}

// batched weight conversion: blockIdx.y selects job
struct CvtJobs { const float* s[9]; u16* d[9]; int n[9]; };
__global__ __launch_bounds__(256) void k_cvtall(CvtJobs j) {
    const int job = blockIdx.y;
    const float* s = j.s[job];
    u16* d = j.d[job];
    const int n = j.n[job];
    for (int i = blockIdx.x * 256 + threadIdx.x; i < n; i += gridDim.x * 256)
        d[i] = f2b(s[i]);
}

// async global->LDS, 16B per lane. LDS dest = wave-uniform base + lane*16.
__device__ __forceinline__ void gload16(const u16* g, u16* l) {
    __builtin_amdgcn_global_load_lds(
        (const __attribute__((address_space(1))) void*)g,
        (__attribute__((address_space(3))) void*)l, 16, 0, 0);
}

// ---------------- MFMA types ----------------
typedef __attribute__((ext_vector_type(8))) __bf16 bf8v;
typedef __attribute__((ext_vector_type(8))) short  s8v;
typedef __attribute__((ext_vector_type(4))) float  f4v;

// ---------------- MFMA input projection ----------------
template<bool DOLN>
__global__ __launch_bounds__(512) void k_inproj(
    const float* __restrict__ x, int row0, int Mloc,
    const u16* __restrict__ w16, const float* __restrict__ bias,
    const float* __restrict__ g, const float* __restrict__ bb,
    u16* __restrict__ outb)
{
    __shared__ u16 Ws[256 * 40];
    __shared__ float Cb[256], Cg[256], Cbb[256];
    const int tid = threadIdx.x, lane = tid & 63, w = tid >> 6;
    const int lr = lane & 15, hi = lane >> 4;

    for (int ch = tid; ch < 1024; ch += 512) {
        int r = ch >> 2, g4 = ch & 3;
        *(uint4*)&Ws[r * 40 + g4 * 8] = *(const uint4*)(w16 + r * 32 + g4 * 8);
    }
    if (tid < 256) {
        Cb[tid] = bias[tid];
        if (DOLN) { Cg[tid] = g[tid]; Cbb[tid] = bb[tid]; }
    }

    const int rloc = blockIdx.x * 128 + w * 16 + lr;
    const int gr = row0 + min(rloc, Mloc - 1);
    bf8v xf;
    {
        const float* xp = x + (size_t)gr * DIN + hi * 8;
        float4 a = *(const float4*)xp, c = *(const float4*)(xp + 4);
        union { s8v s; bf8v b; } u;
        u.s[0] = (short)f2b(a.x); u.s[1] = (short)f2b(a.y);
        u.s[2] = (short)f2b(a.z); u.s[3] = (short)f2b(a.w);
        u.s[4] = (short)f2b(c.x); u.s[5] = (short)f2b(c.y);
        u.s[6] = (short)f2b(c.z); u.s[7] = (short)f2b(c.w);
        xf = u.b;
    }
    __syncthreads();

    f4v acc[16];
    #pragma unroll
    for (int ci = 0; ci < 16; ci++) {
        acc[ci] = (f4v){0.f, 0.f, 0.f, 0.f};
        bf8v af = *(const bf8v*)&Ws[(ci * 16 + lr) * 40 + hi * 8];
        acc[ci] = __builtin_amdgcn_mfma_f32_16x16x32_bf16(af, xf, acc[ci], 0, 0, 0);
    }
    #pragma unroll
    for (int ci = 0; ci < 16; ci++)
        #pragma unroll
        for (int r = 0; r < 4; r++)
            acc[ci][r] += Cb[ci * 16 + hi * 4 + r];

    float mean = 0.f, ri = 1.f;
    if (DOLN) {
        float s = 0.f, q = 0.f;
        #pragma unroll
        for (int ci = 0; ci < 16; ci++)
            #pragma unroll
            for (int r = 0; r < 4; r++) { s += acc[ci][r]; q += acc[ci][r] * acc[ci][r]; }
        s += __shfl_xor(s, 16); s += __shfl_xor(s, 32);
        q += __shfl_xor(q, 16); q += __shfl_xor(q, 32);
        mean = s * (1.f / D);
        float var = q * (1.f / D) - mean * mean;
        ri = rsqrtf(var + 1e-5f);
    }
    if (rloc < Mloc) {
        #pragma unroll
        for (int ci = 0; ci < 16; ci++) {
            float v0[4];
            #pragma unroll
            for (int r = 0; r < 4; r++) {
                float v = acc[ci][r];
                if (DOLN) v = (v - mean) * ri * Cg[ci * 16 + hi * 4 + r] + Cbb[ci * 16 + hi * 4 + r];
                v0[r] = fmaxf(v, 0.f);
            }
            uint2 pkv;
            pkv.x = pk2(v0[0], v0[1]);
            pkv.y = pk2(v0[2], v0[3]);
            *(uint2*)&outb[(size_t)rloc * 256 + ci * 16 + hi * 4] = pkv;
        }
    }
}

// ---------------- row LayerNorm ----------------
__global__ __launch_bounds__(256) void k_ln(
    const float* __restrict__ in, float* __restrict__ out,
    const float* __restrict__ g, const float* __restrict__ b)
{
    const int t = threadIdx.x;
    const int row = blockIdx.x;
    float v = in[(size_t)row * D + t];
    float s = v, q = v * v;
    #pragma unroll
    for (int off = 32; off >= 1; off >>= 1) { s += __shfl_xor(s, off); q += __shfl_xor(q, off); }
    __shared__ float red[2][4];
    const int wid = t >> 6;
    if ((t & 63) == 0) { red[0][wid] = s; red[1][wid] = q; }
    __syncthreads();
    float S = red[0][0] + red[0][1] + red[0][2] + red[0][3];
    float Q = red[1][0] + red[1][1] + red[1][2] + red[1][3];
    float m   = S * (1.f / D);
    float var = Q * (1.f / D) - m * m;
    float ri  = rsqrtf(var + 1e-5f);
    out[(size_t)row * D + t] = (v - m) * ri * g[t] + b[t];
}

__global__ __launch_bounds__(256) void k_bcast(const float* __restrict__ qe, float* __restrict__ q)
{
    const int t = threadIdx.x;
    const int r = blockIdx.x;
    q[(size_t)r * D + t] = qe[(size_t)(r % NQ) * D + t];
}

// ---------------- fp32 tile GEMM (cls head only) ----------------
template<int BM, int BN, int TM, int TN>
__global__ __launch_bounds__(256) void k_gemm(
    const float* __restrict__ A, const float* __restrict__ W,
    const float* __restrict__ bias, const float* __restrict__ resid,
    float* __restrict__ C, int M, int N, int K, int relu)
{
    constexpr int BK = 16;
    constexpr int TX = BN / TN, TY = BM / TM;
    static_assert(TX * TY == 256, "block must be 256 threads");
    __shared__ float As[BK][BM + 4];
    __shared__ float Ws[BK][BN + 4];

    const int tid = threadIdx.x;
    const int tx = tid % TX, ty = tid / TX;
    const int row0 = blockIdx.y * BM, col0 = blockIdx.x * BN;

    float acc[TM][TN];
    #pragma unroll
    for (int i = 0; i < TM; i++)
        #pragma unroll
        for (int j = 0; j < TN; j++) acc[i][j] = 0.f;

    for (int k0 = 0; k0 < K; k0 += BK) {
        __syncthreads();
        for (int idx = tid; idx < BM * (BK / 4); idx += 256) {
            int r = idx / (BK / 4), c4 = idx % (BK / 4);
            int gr = row0 + r;
            float4 v;
            if (gr < M) v = *(const float4*)(A + (size_t)gr * K + k0 + c4 * 4);
            else { v.x = v.y = v.z = v.w = 0.f; }
            As[c4*4+0][r] = v.x; As[c4*4+1][r] = v.y; As[c4*4+2][r] = v.z; As[c4*4+3][r] = v.w;
        }
        for (int idx = tid; idx < BN * (BK / 4); idx += 256) {
            int n = idx / (BK / 4), c4 = idx % (BK / 4);
            int gn = col0 + n;
            float4 v;
            if (gn < N) v = *(const float4*)(W + (size_t)gn * K + k0 + c4 * 4);
            else { v.x = v.y = v.z = v.w = 0.f; }
            Ws[c4*4+0][n] = v.x; Ws[c4*4+1][n] = v.y; Ws[c4*4+2][n] = v.z; Ws[c4*4+3][n] = v.w;
        }
        __syncthreads();
        #pragma unroll
        for (int kk = 0; kk < BK; kk++) {
            float a[TM], bb[TN];
            #pragma unroll
            for (int i = 0; i < TM; i++) a[i] = As[kk][ty * TM + i];
            #pragma unroll
            for (int j = 0; j < TN; j++) bb[j] = Ws[kk][tx * TN + j];
            #pragma unroll
            for (int i = 0; i < TM; i++)
                #pragma unroll
                for (int j = 0; j < TN; j++)
                    acc[i][j] = fmaf(a[i], bb[j], acc[i][j]);
        }
    }

    #pragma unroll
    for (int i = 0; i < TM; i++) {
        int gr = row0 + ty * TM + i;
        if (gr >= M) continue;
        #pragma unroll
        for (int j = 0; j < TN; j++) {
            int gn = col0 + tx * TN + j;
            if (gn >= N) continue;
            float v = acc[i][j];
            if (bias)  v += bias[gn];
            if (resid) v += resid[(size_t)gr * N + gn];
            if (relu)  v = fmaxf(v, 0.f);
            C[(size_t)gr * N + gn] = v;
        }
    }
}

// ---------------- mm_small: bf16 MFMA GEMM, fp32 A (converted in staging), fp32 out ----
template<bool RELU>
__global__ __launch_bounds__(256) void mm_small(
    const float* __restrict__ A, const u16* __restrict__ W,
    const float* __restrict__ bias, const float* __restrict__ resid,
    float* __restrict__ C, int M, int N, int K)
{
    __shared__ u16 As[64 * 40];
    __shared__ u16 Bs[64 * 40];
    const int tid  = threadIdx.x;
    const int lane = tid & 63, w = tid >> 6;
    const int wm = w >> 1, wn = w & 1;
    const int row0 = blockIdx.y * 64, col0 = blockIdx.x * 64;
    const int lr = lane & 15, hi = lane >> 4;

    f4v acc[2][2];
    #pragma unroll
    for (int i = 0; i < 2; i++)
        #pragma unroll
        for (int j = 0; j < 2; j++) acc[i][j] = (f4v){0.f, 0.f, 0.f, 0.f};

    const int sr = tid >> 2, sc = (tid & 3) * 8;
    const int ga = min(row0 + sr, M - 1);
    const int gw = min(col0 + sr, N - 1);

    for (int k0 = 0; k0 < K; k0 += 32) {
        __syncthreads();
        {
            const float* ap = A + (size_t)ga * K + k0 + sc;
            float4 a = *(const float4*)ap, c = *(const float4*)(ap + 4);
            uint4 u;
            u.x = pk2(a.x, a.y); u.y = pk2(a.z, a.w);
            u.z = pk2(c.x, c.y); u.w = pk2(c.z, c.w);
            *(uint4*)&As[sr * 40 + sc] = u;
            *(uint4*)&Bs[sr * 40 + sc] = *(const uint4*)(W + (size_t)gw * K + k0 + sc);
        }
        __syncthreads();
        bf8v a0 = *(const bf8v*)&As[(wm * 32      + lr) * 40 + hi * 8];
        bf8v a1 = *(const bf8v*)&As[(wm * 32 + 16 + lr) * 40 + hi * 8];
        bf8v b0 = *(const bf8v*)&Bs[(wn * 32      + lr) * 40 + hi * 8];
        bf8v b1 = *(const bf8v*)&Bs[(wn * 32 + 16 + lr) * 40 + hi * 8];
        acc[0][0] = __builtin_amdgcn_mfma_f32_16x16x32_bf16(a0, b0, acc[0][0], 0, 0, 0);
        acc[0][1] = __builtin_amdgcn_mfma_f32_16x16x32_bf16(a0, b1, acc[0][1], 0, 0, 0);
        acc[1][0] = __builtin_amdgcn_mfma_f32_16x16x32_bf16(a1, b0, acc[1][0], 0, 0, 0);
        acc[1][1] = __builtin_amdgcn_mfma_f32_16x16x32_bf16(a1, b1, acc[1][1], 0, 0, 0);
    }

    const int crl = hi * 4, ccl = lr;
    #pragma unroll
    for (int mi = 0; mi < 2; mi++)
        #pragma unroll
        for (int ni = 0; ni < 2; ni++)
            #pragma unroll
            for (int r = 0; r < 4; r++) {
                int grow = row0 + wm * 32 + mi * 16 + crl + r;
                int gcol = col0 + wn * 32 + ni * 16 + ccl;
                if (grow < M && gcol < N) {
                    float v = acc[mi][ni][r];
                    if (bias)  v += bias[gcol];
                    if (resid) v += resid[(size_t)grow * N + gcol];
                    if (RELU)  v = fmaxf(v, 0.f);
                    C[(size_t)grow * N + gcol] = v;
                }
            }
}

// ---------------- mm128: bf16 MFMA GEMM 128x128, gload_lds staging + XCD swizzle ----
// (single-buffer, proven round-10/13 structure)
// z-index decomposition: A += (bz%zmod)*sA; W += (bz%zmod)*sW + (bz/zmod)*sW2;
// bias += (bz/zmod)*sBias; C += bz*sC.  OUTBF: coalesced bf16 store via LDS (N%128==0).
template<bool OUTBF>
__global__ __launch_bounds__(256) void mm128(
    const u16* __restrict__ A, const u16* __restrict__ W,
    const float* __restrict__ bias, void* __restrict__ Cv,
    int M, int N, int K, long long sA, long long sW, long long sC,
    int zmod, long long sW2, long long sBias)
{
    __shared__ u16 sm[8192];           // As = sm[0..4096), Bs = sm[4096..8192)
    u16* As = sm;
    u16* Bs = sm + 4096;

    // bijective XCD-aware swizzle (m204) on the flattened block id
    const int gx = gridDim.x, gy = gridDim.y;
    const int total = gx * gy * (int)gridDim.z;
    const int flat = blockIdx.x + gx * (blockIdx.y + gy * blockIdx.z);
    const int q8 = total >> 3, r8 = total & 7;
    const int xcd = flat & 7, blk = flat >> 3;
    const int swz = (xcd < r8 ? xcd * (q8 + 1) : r8 * (q8 + 1) + (xcd - r8) * q8) + blk;
    const int bx = swz % gx, by = (swz / gx) % gy, bz = swz / (gx * gy);

    const int aidx = bz % zmod, widx = bz / zmod;
    A += (size_t)aidx * sA;
    W += (size_t)aidx * sW + (size_t)widx * sW2;
    if (bias) bias += (size_t)widx * sBias;
    const int tid = threadIdx.x, lane = tid & 63, w = tid >> 6;
    const int wm = w >> 1, wn = w & 1;
    const int row0 = by * 128, col0 = bx * 128;
    const int lr = lane & 15, hi = lane >> 4;
    const int srow = lane >> 2, scol = (lane & 3) * 8;

    f4v acc[4][4];
    #pragma unroll
    for (int i = 0; i < 4; i++)
        #pragma unroll
        for (int j = 0; j < 4; j++) acc[i][j] = (f4v){0.f, 0.f, 0.f, 0.f};

    for (int k0 = 0; k0 < K; k0 += 32) {
        __syncthreads();
        #pragma unroll
        for (int i = 0; i < 2; i++) {
            const int c = w * 2 + i;                   // chunk 0..7 (wave-uniform)
            const int row = c * 16 + srow;
            const int gra = min(row0 + row, M - 1);
            const int grb = min(col0 + row, N - 1);
            gload16(A + (size_t)gra * K + k0 + scol, &As[c * 512]);
            gload16(W + (size_t)grb * K + k0 + scol, &Bs[c * 512]);
        }
        __syncthreads();
        bf8v a[4], bb[4];
        #pragma unroll
        for (int mi = 0; mi < 4; mi++)
            a[mi] = *(const bf8v*)&As[(wm * 64 + mi * 16 + lr) * 32 + hi * 8];
        #pragma unroll
        for (int ni = 0; ni < 4; ni++)
            bb[ni] = *(const bf8v*)&Bs[(wn * 64 + ni * 16 + lr) * 32 + hi * 8];
        #pragma unroll
        for (int mi = 0; mi < 4; mi++)
            #pragma unroll
            for (int ni = 0; ni < 4; ni++)
                acc[mi][ni] = __builtin_amdgcn_mfma_f32_16x16x32_bf16(a[mi], bb[ni], acc[mi][ni], 0, 0, 0);
    }

    if (OUTBF) {
        // coalesced store: two 64-row halves through the 16 KB LDS buffer
        #pragma unroll
        for (int h0 = 0; h0 < 2; h0++) {
            __syncthreads();
            if (wm == h0) {
                #pragma unroll
                for (int mi = 0; mi < 4; mi++)
                    #pragma unroll
                    for (int ni = 0; ni < 4; ni++) {
                        int gcol = col0 + wn * 64 + ni * 16 + lr;
                        float bv = bias ? bias[gcol] : 0.f;
                        #pragma unroll
                        for (int r = 0; r < 4; r++) {
                            int lrow = mi * 16 + hi * 4 + r;
                            sm[lrow * 128 + wn * 64 + ni * 16 + lr] = f2b(acc[mi][ni][r] + bv);
                        }
                    }
            }
            __syncthreads();
            u16* Cb16 = (u16*)Cv + (size_t)bz * sC;
            #pragma unroll
            for (int j = 0; j < 4; j++) {
                int idx = tid + j * 256;               // 1024 uint4 = 64 rows x 16
                int lrow = idx >> 4, c16 = idx & 15;
                int grow = row0 + h0 * 64 + lrow;
                if (grow < M)
                    *(uint4*)(Cb16 + (size_t)grow * N + col0 + c16 * 8) =
                        *(const uint4*)&sm[lrow * 128 + c16 * 8];
            }
        }
    } else {
        const int crl = hi * 4, ccl = lr;
        float* Cf = (float*)Cv + (size_t)bz * sC;
        #pragma unroll
        for (int mi = 0; mi < 4; mi++)
            #pragma unroll
            for (int ni = 0; ni < 4; ni++)
                #pragma unroll
                for (int r = 0; r < 4; r++) {
                    int grow = row0 + wm * 64 + mi * 16 + crl + r;
                    int gcol = col0 + wn * 64 + ni * 16 + ccl;
                    if (grow < M && gcol < N) {
                        float v = acc[mi][ni][r];
                        if (bias) v += bias[gcol];
                        Cf[(size_t)grow * N + gcol] = v;
                    }
                }
    }
}

// ---------------- MFMA flash cross-attention (64-key steps, z-batched) ----------------
__global__ __launch_bounds__(512) void k_flash(
    const float* __restrict__ qbuf, const u16* __restrict__ kv,
    float* __restrict__ part, int bBase, size_t kvStride, size_t pStride)
{
    const int tid = threadIdx.x;
    const int lane = tid & 63, w = tid >> 6;
    const int h = blockIdx.y;
    const int b = bBase + blockIdx.z;
    const u16* kvp = kv + (size_t)blockIdx.z * kvStride;
    float* pp = part + (size_t)blockIdx.z * pStride;
    const int k0loc = blockIdx.x * CHUNK;
    const int lr = lane & 15, hi = lane >> 4;

    __shared__ u16 Ks[64 * 40];
    __shared__ u16 Vt[32 * 72];
    __shared__ u16 Pt[8][16 * 72];

    const int qt = w * 16 + lr;
    const int qg = b * NQ + min(qt, NQ - 1);
    bf8v qf;
    {
        const float* Qp = qbuf + (size_t)qg * D + h * DH + hi * 8;
        union { s8v s; bf8v b; } qu;
        #pragma unroll
        for (int j = 0; j < 8; j++) qu.s[j] = (short)f2b(Qp[j] * SM_SCALE);
        qf = qu.b;
    }

    float m = -1e30f, l = 0.f;
    f4v o0 = (f4v){0.f,0.f,0.f,0.f}, o1 = (f4v){0.f,0.f,0.f,0.f};

    constexpr int NSTEP = (CHUNK + 63) / 64;   // 20
    for (int s = 0; s < NSTEP; s++) {
        const int ck = k0loc + s * 64;
        const int nv = min(64, k0loc + CHUNK - ck);
        __syncthreads();
        if (tid < 256) {
            int key = tid >> 2, g = tid & 3;
            int krow = min(ck + key, Ni - 1);
            *(uint4*)&Ks[key * 40 + g * 8] =
                *(const uint4*)(kvp + (size_t)krow * (2 * D) + h * DH + g * 8);
        } else {
            int t2 = tid - 256;
            int key = t2 >> 2, g = t2 & 3;
            int krow = min(ck + key, Ni - 1);
            uint4 u = *(const uint4*)(kvp + (size_t)krow * (2 * D) + D + h * DH + g * 8);
            const u16* pu = (const u16*)&u;
            #pragma unroll
            for (int j = 0; j < 8; j++) Vt[(g * 8 + j) * 72 + key] = pu[j];
        }
        __syncthreads();

        f4v sf[4];
        #pragma unroll
        for (int j = 0; j < 4; j++) {
            bf8v kf = *(const bf8v*)&Ks[(j * 16 + lr) * 40 + hi * 8];
            sf[j] = (f4v){0.f,0.f,0.f,0.f};
            sf[j] = __builtin_amdgcn_mfma_f32_16x16x32_bf16(kf, qf, sf[j], 0, 0, 0);
        }

        float sv[16];
        #pragma unroll
        for (int j = 0; j < 4; j++)
            #pragma unroll
            for (int r = 0; r < 4; r++) {
                int key0 = j * 16 + hi * 4 + r;
                sv[j * 4 + r] = (key0 < nv) ? sf[j][r] : -1e30f;
            }
        float smax = sv[0];
        #pragma unroll
        for (int j = 1; j < 16; j++) smax = fmaxf(smax, sv[j]);
        smax = fmaxf(smax, __shfl_xor(smax, 16));
        smax = fmaxf(smax, __shfl_xor(smax, 32));
        float mnew  = fmaxf(m, smax);
        float scale = __expf(m - mnew);
        m = mnew;

        float pv[16];
        float psum = 0.f;
        #pragma unroll
        for (int j = 0; j < 16; j++) {
            pv[j] = __expf(sv[j] - mnew);
            psum += pv[j];
        }
        psum += __shfl_xor(psum, 16);
        psum += __shfl_xor(psum, 32);
        l = l * scale + psum;

        u16* pw = &Pt[w][lr * 72];
        #pragma unroll
        for (int j = 0; j < 4; j++) {
            *(u32*)&pw[j * 16 + hi * 4]     = pk2(pv[j*4+0], pv[j*4+1]);
            *(u32*)&pw[j * 16 + hi * 4 + 2] = pk2(pv[j*4+2], pv[j*4+3]);
        }

        const int qb4 = hi * 4;
        float f0 = __shfl(scale, qb4 + 0);
        float f1 = __shfl(scale, qb4 + 1);
        float f2 = __shfl(scale, qb4 + 2);
        float f3 = __shfl(scale, qb4 + 3);
        o0[0] *= f0; o0[1] *= f1; o0[2] *= f2; o0[3] *= f3;
        o1[0] *= f0; o1[1] *= f1; o1[2] *= f2; o1[3] *= f3;

        #pragma unroll
        for (int j = 0; j < 2; j++) {
            bf8v pf  = *(const bf8v*)&Pt[w][lr * 72 + j * 32 + hi * 8];
            bf8v vf0 = *(const bf8v*)&Vt[lr * 72 + j * 32 + hi * 8];
            bf8v vf1 = *(const bf8v*)&Vt[(16 + lr) * 72 + j * 32 + hi * 8];
            o0 = __builtin_amdgcn_mfma_f32_16x16x32_bf16(pf, vf0, o0, 0, 0, 0);
            o1 = __builtin_amdgcn_mfma_f32_16x16x32_bf16(pf, vf1, o1, 0, 0, 0);
        }
    }

    const size_t pbase = ((size_t)(h * NCHUNK + blockIdx.x) * 128) * 34;
    #pragma unroll
    for (int r = 0; r < 4; r++) {
        int qtr = w * 16 + hi * 4 + r;
        pp[pbase + (size_t)qtr * 34 + 2 + lr]      = o0[r];
        pp[pbase + (size_t)qtr * 34 + 2 + 16 + lr] = o1[r];
    }
    if (lane < 16) {
        pp[pbase + (size_t)(w * 16 + lane) * 34 + 0] = m;
        pp[pbase + (size_t)(w * 16 + lane) * 34 + 1] = l;
    }
}

__global__ __launch_bounds__(64) void k_fmerge(const float* __restrict__ part,
                                               float* __restrict__ abuf, int bBase, size_t pStride)
{
    const float* pz = part + (size_t)blockIdx.y * pStride;
    const int b = bBase + blockIdx.y;
    const int t = threadIdx.x;
    const int hq = blockIdx.x;
    const int h = hq / NQ, q = hq % NQ;
    float mmax = -1e30f;
    for (int c = 0; c < NCHUNK; c++)
        mmax = fmaxf(mmax, pz[((size_t)(h * NCHUNK + c) * 128 + q) * 34]);
    float L = 0.f, a = 0.f;
    for (int c = 0; c < NCHUNK; c++) {
        const float* p = &pz[((size_t)(h * NCHUNK + c) * 128 + q) * 34];
        float wv = __expf(p[0] - mmax);
        L += wv * p[1];
        if (t < DH) a += wv * p[2 + t];
    }
    if (t < DH)
        abuf[((size_t)(b * NQ + q)) * D + h * DH + t] = a / L;
}

// ---------------- self-attention (100x100 per (b,h)) ----------------
__global__ __launch_bounds__(128) void k_sattn(const float* __restrict__ sqkv, float* __restrict__ abuf)
{
    const int tid = threadIdx.x;
    const int bh = blockIdx.x;
    const int b = bh >> 3, h = bh & 7;
    __shared__ float Ks[NQ][DH], Vs[NQ][DH];
    for (int idx = tid; idx < NQ * 8; idx += 128) {
        int kk = idx >> 3, f4 = idx & 7;
        const float* base = sqkv + ((size_t)(b * NQ + kk)) * (3 * D) + h * DH;
        *(float4*)&Ks[kk][f4 * 4] = *(const float4*)(base + D + f4 * 4);
        *(float4*)&Vs[kk][f4 * 4] = *(const float4*)(base + 2 * D + f4 * 4);
    }
    float qr[DH];
    const int q = tid;
    if (q < NQ) {
        const float* Qp = sqkv + ((size_t)(b * NQ + q)) * (3 * D) + h * DH;
        #pragma unroll
        for (int d = 0; d < DH; d += 4) {
            float4 v = *(const float4*)(Qp + d);
            qr[d] = v.x * SM_SCALE; qr[d+1] = v.y * SM_SCALE;
            qr[d+2] = v.z * SM_SCALE; qr[d+3] = v.w * SM_SCALE;
        }
    } else {
        #pragma unroll
        for (int d = 0; d < DH; d++) qr[d] = 0.f;
    }
    __syncthreads();
    float m = -1e30f, l = 0.f, acc[DH];
    #pragma unroll
    for (int d = 0; d < DH; d++) acc[d] = 0.f;
    for (int kk = 0; kk < NQ; kk++) {
        float sc = 0.f;
        #pragma unroll
        for (int d = 0; d < DH; d++) sc += qr[d] * Ks[kk][d];
        if (sc > m) {
            float r = __expf(m - sc);
            l *= r;
            #pragma unroll
            for (int d = 0; d < DH; d++) acc[d] *= r;
            m = sc;
        }
        float p = __expf(sc - m);
        l += p;
        #pragma unroll
        for (int d = 0; d < DH; d++) acc[d] += p * Vs[kk][d];
    }
    if (q < NQ) {
        float li = 1.f / l;
        float* o = abuf + ((size_t)(b * NQ + q)) * D + h * DH;
        #pragma unroll
        for (int d = 0; d < DH; d++) o[d] = acc[d] * li;
    }
}

// ---------------- host ----------------
extern "C" void kernel_launch(void* const* d_in, const int* in_sizes, int n_in,
                              void* d_out, int out_size, void* d_ws, size_t ws_size,
                              hipStream_t stream)
{
    const float* x        = (const float*)d_in[0];
    const float* ip_w     = (const float*)d_in[2];
    const float* ip_b     = (const float*)d_in[3];
    const float* ip_g     = (const float*)d_in[4];
    const float* ip_bb    = (const float*)d_in[5];
    const float* xm_w1    = (const float*)d_in[6];
    const float* xm_b1    = (const float*)d_in[7];
    const float* xm_w2    = (const float*)d_in[8];
    const float* xm_b2    = (const float*)d_in[9];
    const float* qe       = (const float*)d_in[10];
    const float* ca_wqkv  = (const float*)d_in[11];
    const float* ca_bqkv  = (const float*)d_in[12];
    const float* ca_wo    = (const float*)d_in[13];
    const float* ca_bo    = (const float*)d_in[14];
    const float* sa_wqkv  = (const float*)d_in[15];
    const float* sa_bqkv  = (const float*)d_in[16];
    const float* sa_wo    = (const float*)d_in[17];
    const float* sa_bo    = (const float*)d_in[18];
    const float* sa_ln_g  = (const float*)d_in[19];
    const float* sa_ln_b  = (const float*)d_in[20];
    const float* ffn_w1   = (const float*)d_in[21];
    const float* ffn_b1   = (const float*)d_in[22];
    const float* ffn_w2   = (const float*)d_in[23];
    const float* ffn_b2   = (const float*)d_in[24];
    const float* ffn_ln_g = (const float*)d_in[25];
    const float* ffn_ln_b = (const float*)d_in[26];
    const float* out_ln_g = (const float*)d_in[27];
    const float* out_ln_b = (const float*)d_in[28];
    const float* cls_w1   = (const float*)d_in[29];
    const float* cls_b1   = (const float*)d_in[30];
    const float* cls_w2   = (const float*)d_in[31];
    const float* cls_b2   = (const float*)d_in[32];
    float* out = (float*)d_out;

    // ---- workspace tiering (measured: ws in [210, 430) MB -> kvG=1 batched) ----
    bool batched = false;
    int kvG = 1;
    int instRows;
    if      (ws_size >= 740000000ull) { batched = true; kvG = 6; instRows = BNi; }
    else if (ws_size >= 430000000ull) { batched = true; kvG = 3; instRows = BNi; }
    else if (ws_size >= 210000000ull) { batched = true; kvG = 1; instRows = BNi; }
    else if (ws_size >= 112000000ull) { instRows = BNi; }
    else if (ws_size >=  73000000ull) { instRows = Ni;  }
    else return;
    const bool instFull = (instRows == BNi);
    const int nzb = batched ? Bz : 1;

    char* wp = (char*)d_ws;
    auto alloc = [&](size_t bytes) -> char* {
        char* r = wp; wp += (bytes + 255) & ~(size_t)255; return r;
    };
    u16*   instb = (u16*)  alloc((size_t)instRows * D * 2);
    u16*   kvb   = (u16*)  alloc((batched ? (size_t)kvG * Bz * Ni * 2 * D : (size_t)Ni * 2 * D) * 2);
    float* part  = (float*)alloc((size_t)nzb * PARTB * 4);
    float* qbuf  = (float*)alloc(409600);
    float* abuf  = (float*)alloc(409600);
    float* sqkv  = (float*)alloc(1228800);
    float* f1b   = (float*)alloc(1638400);
    float* qA    = (float*)alloc(409600);
    float* qB    = (float*)alloc(409600);
    u16*   ipw16 = (u16*)  alloc(256 * 32 * 2);
    u16*   xw116 = (u16*)  alloc(256 * 32 * 2);
    u16*   xw216 = (u16*)  alloc((size_t)D * D * 2);
    u16*   caq16 = (u16*)  alloc((size_t)Ll * 3 * D * D * 2);
    u16*   saq16 = (u16*)  alloc((size_t)Ll * 3 * D * D * 2);
    u16*   cao16 = (u16*)  alloc((size_t)Ll * D * D * 2);
    u16*   sao16 = (u16*)  alloc((size_t)Ll * D * D * 2);
    u16*   fw116 = (u16*)  alloc((size_t)Ll * HIDd * D * 2);
    u16*   fw216 = (u16*)  alloc((size_t)Ll * D * HIDd * 2);
    u16*   qnb   = (u16*)  alloc((size_t)Bz * NQ * D * 2);

    // single-launch weight conversion (9 jobs)
    {
        CvtJobs j;
        j.s[0] = ip_w;    j.d[0] = ipw16; j.n[0] = 256 * 32;
        j.s[1] = xm_w1;   j.d[1] = xw116; j.n[1] = 256 * 32;
        j.s[2] = xm_w2;   j.d[2] = xw216; j.n[2] = D * D;
        j.s[3] = ca_wqkv; j.d[3] = caq16; j.n[3] = Ll * 3 * D * D;
        j.s[4] = sa_wqkv; j.d[4] = saq16; j.n[4] = Ll * 3 * D * D;
        j.s[5] = ca_wo;   j.d[5] = cao16; j.n[5] = Ll * D * D;
        j.s[6] = sa_wo;   j.d[6] = sao16; j.n[6] = Ll * D * D;
        j.s[7] = ffn_w1;  j.d[7] = fw116; j.n[7] = Ll * HIDd * D;
        j.s[8] = ffn_w2;  j.d[8] = fw216; j.n[8] = Ll * D * HIDd;
        k_cvtall<<<dim3(48, 9), 256, 0, stream>>>(j);
    }

    if (instFull)
        k_inproj<true><<<(BNi + 127) / 128, 512, 0, stream>>>(
            x, 0, BNi, ipw16, ip_b, ip_g, ip_bb, instb);
    k_bcast<<<Bz * NQ, 256, 0, stream>>>(qe, qA);

    float* qcur = qA;
    float* qtmp = qB;

    auto layer_tail = [&](int i) {
        mm_small<false><<<dim3(4, 7), 256, 0, stream>>>(
            abuf, cao16 + (size_t)i * D * D, ca_bo + (size_t)i * D, qcur, qtmp,
            Bz * NQ, D, D);
        { float* t2 = qcur; qcur = qtmp; qtmp = t2; }
        mm_small<false><<<dim3(12, 7), 256, 0, stream>>>(
            qcur, saq16 + (size_t)i * 3 * D * D, sa_bqkv + (size_t)i * 3 * D, nullptr, sqkv,
            Bz * NQ, 3 * D, D);
        k_sattn<<<Bz * Hh, 128, 0, stream>>>(sqkv, abuf);
        mm_small<false><<<dim3(4, 7), 256, 0, stream>>>(
            abuf, sao16 + (size_t)i * D * D, sa_bo + (size_t)i * D, qcur, qtmp,
            Bz * NQ, D, D);
        k_ln<<<Bz * NQ, 256, 0, stream>>>(qtmp, qtmp, sa_ln_g + i * D, sa_ln_b + i * D);
        { float* t2 = qcur; qcur = qtmp; qtmp = t2; }
        mm_small<true><<<dim3(16, 7), 256, 0, stream>>>(
            qcur, fw116 + (size_t)i * HIDd * D, ffn_b1 + (size_t)i * HIDd, nullptr, f1b,
            Bz * NQ, HIDd, D);
        mm_small<false><<<dim3(4, 7), 256, 0, stream>>>(
            f1b, fw216 + (size_t)i * D * HIDd, ffn_b2 + (size_t)i * D, qcur, qtmp,
            Bz * NQ, D, HIDd);
        k_ln<<<Bz * NQ, 256, 0, stream>>>(qtmp, qtmp, ffn_ln_g + i * D, ffn_ln_b + i * D);
        { float* t2 = qcur; qcur = qtmp; qtmp = t2; }
    };

    if (batched) {
        for (int l0 = 0; l0 < Ll; l0 += kvG) {
            mm128<true><<<dim3(4, 196, 4 * kvG), 256, 0, stream>>>(
                instb, caq16 + (size_t)l0 * 3 * D * D + (size_t)D * D,
                ca_bqkv + (size_t)l0 * 3 * D + D, kvb, Ni, 2 * D, D,
                (long long)Ni * D, 0, (long long)Ni * 2 * D,
                4, (long long)3 * D * D, (long long)3 * D);
            for (int i = l0; i < l0 + kvG; i++) {
                const u16* wq16 = caq16 + (size_t)i * 3 * D * D;
                const float* bqkv = ca_bqkv + (size_t)i * 3 * D;
                mm_small<false><<<dim3(4, 7), 256, 0, stream>>>(
                    qcur, wq16, bqkv, nullptr, qbuf, Bz * NQ, D, D);
                const u16* kvl = kvb + (size_t)(i - l0) * Bz * Ni * 2 * D;
                k_flash<<<dim3(NCHUNK, Hh, 4), 512, 0, stream>>>(
                    qbuf, kvl, part, 0, (size_t)Ni * 2 * D, PARTB);
                k_fmerge<<<dim3(Hh * NQ, 4), 64, 0, stream>>>(part, abuf, 0, PARTB);
                layer_tail(i);
            }
        }
    } else {
        for (int i = 0; i < Ll; i++) {
            const u16* wq16  = caq16 + (size_t)i * 3 * D * D;
            const u16* wkv16 = wq16 + (size_t)D * D;
            const float* bqkv = ca_bqkv + (size_t)i * 3 * D;
            mm_small<false><<<dim3(4, 7), 256, 0, stream>>>(
                qcur, wq16, bqkv, nullptr, qbuf, Bz * NQ, D, D);
            for (int b = 0; b < Bz; b++) {
                if (!instFull)
                    k_inproj<true><<<(Ni + 127) / 128, 512, 0, stream>>>(
                        x, b * Ni, Ni, ipw16, ip_b, ip_g, ip_bb, instb);
                const u16* ip = instFull ? instb + (size_t)b * Ni * D : instb;
                mm128<true><<<dim3(4, 196, 1), 256, 0, stream>>>(
                    ip, wkv16, bqkv + D, kvb, Ni, 2 * D, D, 0, 0, 0, 4, 0, 0);
                k_flash<<<dim3(NCHUNK, Hh, 1), 512, 0, stream>>>(
                    qbuf, kvb, part, b, 0, 0);
                k_fmerge<<<dim3(Hh * NQ, 1), 64, 0, stream>>>(part, abuf, b, 0);
            }
            layer_tail(i);
        }
    }

    // final LN into qbuf
    float* qn = qbuf;
    k_ln<<<Bz * NQ, 256, 0, stream>>>(qcur, qn, out_ln_g, out_ln_b);
    // classification head (fp32)
    k_gemm<64,64,4,4><<<dim3(4, 7), 256, 0, stream>>>(
        qn, cls_w1, cls_b1, nullptr, abuf, Bz * NQ, D, D, 1);
    k_gemm<64,64,4,4><<<dim3(1, 7), 256, 0, stream>>>(
        abuf, cls_w2, cls_b2, nullptr, out, Bz * NQ, NC1, D, 0);

    // mask path (instb/kvb regions dead now)
    k_cvt<<<128, 256, 0, stream>>>(qn, qnb, Bz * NQ * D);
    if (instFull) {
        k_inproj<false><<<(BNi + 127) / 128, 512, 0, stream>>>(
            x, 0, BNi, xw116, xm_b1, nullptr, nullptr, instb);
        if (batched) {
            mm128<true><<<dim3(2, 196, 4), 256, 0, stream>>>(
                instb, xw216, xm_b2, kvb, Ni, D, D,
                (long long)Ni * D, 0, (long long)Ni * D, 4, 0, 0);
            mm128<false><<<dim3(196, 1, 4), 256, 0, stream>>>(
                qnb, kvb, nullptr, out + Bz * NQ * NC1, NQ, Ni, D,
                (long long)NQ * D, (long long)Ni * D, (long long)NQ * Ni, 4, 0, 0);
        } else {
            for (int b = 0; b < Bz; b++) {
                mm128<true><<<dim3(2, 196, 1), 256, 0, stream>>>(
                    instb + (size_t)b * Ni * D, xw216, xm_b2, kvb, Ni, D, D, 0, 0, 0, 4, 0, 0);
                mm128<false><<<dim3(196, 1, 1), 256, 0, stream>>>(
                    qnb + (size_t)b * NQ * D, kvb, nullptr,
                    out + Bz * NQ * NC1 + (size_t)b * NQ * Ni, NQ, Ni, D, 0, 0, 0, 4, 0, 0);
            }
        }
    } else {
        for (int b = 0; b < Bz; b++) {
            k_inproj<false><<<(Ni + 127) / 128, 512, 0, stream>>>(
                x, b * Ni, Ni, xw116, xm_b1, nullptr, nullptr, instb);
            mm128<true><<<dim3(2, 196, 1), 256, 0, stream>>>(
                instb, xw216, xm_b2, kvb, Ni, D, D, 0, 0, 0, 4, 0, 0);
            mm128<false><<<dim3(196, 1, 1), 256, 0, stream>>>(
                qnb + (size_t)b * NQ * D, kvb, nullptr,
                out + Bz * NQ * NC1 + (size_t)b * NQ * Ni, NQ, Ni, D, 0, 0, 0, 4, 0, 0);
        }
    }
}